// Round 2
// baseline (102.230 us; speedup 1.0000x reference)
//
#include <hip/hip_runtime.h>
#include <math.h>

#define N_NODES 1024
#define DIM     256

// ---------------------------------------------------------------------------
// Kernel 1: At[d][i] = sum_k nodes[i,k]*W1[d,k]      + b1[d]   (d,k in [0,256))
//           Bt[d][i] = sum_k nodes[i,k]*W1[d,256+k]
// Outputs stored TRANSPOSED ([d][node]) so kernel 2 can stage outer-product
// tiles with coalesced loads.
// Grid: 256 blocks = 32 i-tiles (x) * 8 d-tiles. Block 256 threads, 32x32 tile,
// micro 2x2 per thread (for A and B each), k-chunk 64.
// ---------------------------------------------------------------------------
__global__ __launch_bounds__(256) void k1_gemm(
    const float* __restrict__ nodes, const float* __restrict__ W1,
    const float* __restrict__ b1, float* __restrict__ At, float* __restrict__ Bt)
{
    // stride 34 keeps float2 reads 8B-aligned and bank-spread
    __shared__ float nt[64][34];
    __shared__ float wa[64][34];
    __shared__ float wb[64][34];

    const int i0 = (blockIdx.x & 31) * 32;   // node-index tile
    const int d0 = (blockIdx.x >> 5) * 32;   // feature-index tile
    const int t  = threadIdx.x;
    const int tx = t & 15;                   // -> i pair
    const int ty = t >> 4;                   // -> d pair

    float aA00=0.f,aA01=0.f,aA10=0.f,aA11=0.f;
    float aB00=0.f,aB01=0.f,aB10=0.f,aB11=0.f;

    const int r = t >> 3;          // 0..31 (row within tile)
    const int c = (t & 7) * 8;     // 0..56 (k offset, 8 floats)

    for (int k0 = 0; k0 < DIM; k0 += 64) {
        const float* sn = nodes + (i0 + r) * DIM + k0 + c;
        float4 n0 = *(const float4*)(sn);
        float4 n1 = *(const float4*)(sn + 4);
        const float* sa = W1 + (d0 + r) * (2 * DIM) + k0 + c;
        float4 a0 = *(const float4*)(sa);
        float4 a1 = *(const float4*)(sa + 4);
        const float* sb = sa + DIM;
        float4 q0 = *(const float4*)(sb);
        float4 q1 = *(const float4*)(sb + 4);

        __syncthreads();   // previous chunk's readers done before overwrite

        nt[c+0][r]=n0.x; nt[c+1][r]=n0.y; nt[c+2][r]=n0.z; nt[c+3][r]=n0.w;
        nt[c+4][r]=n1.x; nt[c+5][r]=n1.y; nt[c+6][r]=n1.z; nt[c+7][r]=n1.w;
        wa[c+0][r]=a0.x; wa[c+1][r]=a0.y; wa[c+2][r]=a0.z; wa[c+3][r]=a0.w;
        wa[c+4][r]=a1.x; wa[c+5][r]=a1.y; wa[c+6][r]=a1.z; wa[c+7][r]=a1.w;
        wb[c+0][r]=q0.x; wb[c+1][r]=q0.y; wb[c+2][r]=q0.z; wb[c+3][r]=q0.w;
        wb[c+4][r]=q1.x; wb[c+5][r]=q1.y; wb[c+6][r]=q1.z; wb[c+7][r]=q1.w;

        __syncthreads();

        #pragma unroll 16
        for (int k = 0; k < 64; ++k) {
            float2 av = *(const float2*)&nt[k][tx*2];
            float2 pv = *(const float2*)&wa[k][ty*2];
            float2 qv = *(const float2*)&wb[k][ty*2];
            aA00 += av.x*pv.x; aA01 += av.x*pv.y;
            aA10 += av.y*pv.x; aA11 += av.y*pv.y;
            aB00 += av.x*qv.x; aB01 += av.x*qv.y;
            aB10 += av.y*qv.x; aB11 += av.y*qv.y;
        }
    }

    const int i = i0 + tx*2;
    const int d = d0 + ty*2;
    const float bb0 = b1[d], bb1 = b1[d+1];
    At[(d  )*N_NODES + i  ] = aA00 + bb0;
    At[(d+1)*N_NODES + i  ] = aA01 + bb1;
    At[(d  )*N_NODES + i+1] = aA10 + bb0;
    At[(d+1)*N_NODES + i+1] = aA11 + bb1;
    Bt[(d  )*N_NODES + i  ] = aB00;
    Bt[(d+1)*N_NODES + i  ] = aB01;
    Bt[(d  )*N_NODES + i+1] = aB10;
    Bt[(d+1)*N_NODES + i+1] = aB11;
}

// ---------------------------------------------------------------------------
// Kernel 2: out[i,j] = sigmoid( sum_d relu(At[d][i] + Bt[d][j]) * w2[d] + b2 )
// Grid: 16 x 16 = 256 blocks (one per CU), 64x64 output tile, 256 threads,
// 4x4 micro-tile. d-chunked LDS staging (64 per chunk).
// ---------------------------------------------------------------------------
__global__ __launch_bounds__(256) void k2_pair(
    const float* __restrict__ At, const float* __restrict__ Bt,
    const float* __restrict__ W2, const float* __restrict__ b2,
    float* __restrict__ out)
{
    // stride 68 floats = 272B: keeps per-row float4 16B-aligned, <=2-way bank alias
    __shared__ float As[64][68];
    __shared__ float Bs[64][68];
    __shared__ float w2s[DIM];

    const int i0 = (blockIdx.x & 15) * 64;   // output rows   (A side)
    const int j0 = (blockIdx.x >> 4) * 64;   // output cols   (B side)
    const int t  = threadIdx.x;
    const int tx = t & 15;   // -> j (4 cols)
    const int ty = t >> 4;   // -> i (4 rows)

    w2s[t] = W2[t];          // DIM == blockDim == 256

    float acc[4][4] = {{0.f,0.f,0.f,0.f},{0.f,0.f,0.f,0.f},
                       {0.f,0.f,0.f,0.f},{0.f,0.f,0.f,0.f}};

    const int r = t >> 2;          // 0..63  (d row within chunk)
    const int c = (t & 3) * 16;    // 0,16,32,48

    for (int dc = 0; dc < DIM; dc += 64) {
        const float* sa = At + (dc + r) * N_NODES + i0 + c;
        const float* sb = Bt + (dc + r) * N_NODES + j0 + c;
        float4 va0 = *(const float4*)(sa);
        float4 va1 = *(const float4*)(sa + 4);
        float4 va2 = *(const float4*)(sa + 8);
        float4 va3 = *(const float4*)(sa + 12);
        float4 vb0 = *(const float4*)(sb);
        float4 vb1 = *(const float4*)(sb + 4);
        float4 vb2 = *(const float4*)(sb + 8);
        float4 vb3 = *(const float4*)(sb + 12);

        __syncthreads();   // previous chunk consumed

        *(float4*)&As[r][c   ] = va0;
        *(float4*)&As[r][c+ 4] = va1;
        *(float4*)&As[r][c+ 8] = va2;
        *(float4*)&As[r][c+12] = va3;
        *(float4*)&Bs[r][c   ] = vb0;
        *(float4*)&Bs[r][c+ 4] = vb1;
        *(float4*)&Bs[r][c+ 8] = vb2;
        *(float4*)&Bs[r][c+12] = vb3;

        __syncthreads();

        #pragma unroll 16
        for (int k = 0; k < 64; ++k) {
            float4 a4 = *(const float4*)&As[k][ty*4];
            float4 b4 = *(const float4*)&Bs[k][tx*4];
            float  w  = w2s[dc + k];
            acc[0][0] += fmaxf(a4.x + b4.x, 0.f) * w;
            acc[0][1] += fmaxf(a4.x + b4.y, 0.f) * w;
            acc[0][2] += fmaxf(a4.x + b4.z, 0.f) * w;
            acc[0][3] += fmaxf(a4.x + b4.w, 0.f) * w;
            acc[1][0] += fmaxf(a4.y + b4.x, 0.f) * w;
            acc[1][1] += fmaxf(a4.y + b4.y, 0.f) * w;
            acc[1][2] += fmaxf(a4.y + b4.z, 0.f) * w;
            acc[1][3] += fmaxf(a4.y + b4.w, 0.f) * w;
            acc[2][0] += fmaxf(a4.z + b4.x, 0.f) * w;
            acc[2][1] += fmaxf(a4.z + b4.y, 0.f) * w;
            acc[2][2] += fmaxf(a4.z + b4.z, 0.f) * w;
            acc[2][3] += fmaxf(a4.z + b4.w, 0.f) * w;
            acc[3][0] += fmaxf(a4.w + b4.x, 0.f) * w;
            acc[3][1] += fmaxf(a4.w + b4.y, 0.f) * w;
            acc[3][2] += fmaxf(a4.w + b4.z, 0.f) * w;
            acc[3][3] += fmaxf(a4.w + b4.w, 0.f) * w;
        }
    }

    const float bb = b2[0];
    #pragma unroll
    for (int m = 0; m < 4; ++m) {
        float4 o;
        float x0 = acc[m][0] + bb;
        float x1 = acc[m][1] + bb;
        float x2 = acc[m][2] + bb;
        float x3 = acc[m][3] + bb;
        o.x = 1.0f / (1.0f + __expf(-x0));
        o.y = 1.0f / (1.0f + __expf(-x1));
        o.z = 1.0f / (1.0f + __expf(-x2));
        o.w = 1.0f / (1.0f + __expf(-x3));
        *(float4*)&out[(i0 + ty*4 + m) * N_NODES + j0 + tx*4] = o;
    }
}

extern "C" void kernel_launch(void* const* d_in, const int* in_sizes, int n_in,
                              void* d_out, int out_size, void* d_ws, size_t ws_size,
                              hipStream_t stream) {
    const float* nodes = (const float*)d_in[0];   // (1024, 256)
    const float* W1    = (const float*)d_in[1];   // (256, 512)
    const float* b1    = (const float*)d_in[2];   // (256,)
    const float* W2    = (const float*)d_in[3];   // (1, 256)
    const float* b2    = (const float*)d_in[4];   // (1,)
    float* out = (float*)d_out;                   // (1024, 1024)

    float* At = (float*)d_ws;                     // [256][1024] = 1 MB
    float* Bt = At + DIM * N_NODES;               // [256][1024] = 1 MB

    k1_gemm<<<256, 256, 0, stream>>>(nodes, W1, b1, At, Bt);
    k2_pair<<<256, 256, 0, stream>>>(At, Bt, W2, b2, out);
}